// Round 19
// baseline (115.675 us; speedup 1.0000x reference)
//
#include <hip/hip_runtime.h>
#include <math.h>

#define BB 16
#define TT 4096
#define EE 1024
#define HALF 2048
#define WIN 15
#define EPSF 1e-6f
#define PI_F   3.14159265358979323846f
#define PIO2_F 1.57079632679489662f

// Minimal-issue branchless asin of clamp(t): ~18 VALU slots, raw HW sqrt.
__device__ __forceinline__ float asin_clamped(float t, float LO, float HI) {
    float c  = __builtin_amdgcn_fmed3f(t, LO, HI);   // clamp (1 op, no NaN here)
    float a  = fabsf(c);
    float z1 = c * c;
    float z2 = fmaf(a, -0.5f, 0.5f);                 // (1-a)/2
    bool big = a > 0.5f;
    float z  = big ? z2 : z1;
    float sq;
    asm("v_sqrt_f32 %0, %1" : "=v"(sq) : "v"(z2));   // raw, no IEEE fixup chain
    float s  = big ? sq : a;                         // s in [0, 0.5]
    float p = fmaf(z, 4.2163199048e-2f, 2.4181311049e-2f);
    p = fmaf(z, p, 4.5470025998e-2f);
    p = fmaf(z, p, 7.4953002686e-2f);
    p = fmaf(z, p, 1.6666752422e-1f);
    float r  = fmaf(s * z, p, s);                    // asin(s)
    float rb = fmaf(-2.0f, r, PIO2_F);               // pi/2 - 2*asin(s)
    r = big ? rb : r;
    return copysignf(r, c);
}

// ---------------------------------------------------------------------------
// Phase + fused tdiff (R15 frontier, verbatim): wave per row, b-major out.
// ---------------------------------------------------------------------------
__global__ void phase_tdiff_kernel(const float* __restrict__ x,
                                   const float* __restrict__ taper,
                                   float* __restrict__ phases_b,
                                   float* __restrict__ tdiff_b) {
    const int wave = threadIdx.x >> 6;
    const int lane = threadIdx.x & 63;
    const int row  = blockIdx.x * 4 + wave;      // [0, B*T)
    const int b = row >> 12;
    const int t = row & (TT - 1);
    const float tap = taper[t];
    const float* xr = x + (size_t)row * EE;

    float xd = 0.0f, tapd = 0.0f;
    const int td = t - lane;
    const bool do_d = (lane >= 1) && (lane <= WIN) && (lane <= t);
    if (do_d) {
        xd   = x[((size_t)b * TT + td) * EE];    // element 0 of row t-lane
        tapd = taper[td];
    }

    const float c0 = xr[0] * tap;
    const float r = fabsf(c0) + EPSF;
    const float scale = tap / r;
    const float start = (c0 >= 0.0f) ? 0.0f : PI_F;
    const float LO = -1.0f + EPSF, HI = 1.0f - EPSF;

    const float4* xr4 = (const float4*)xr;
    float sum = 0.0f;
    #pragma unroll
    for (int j = 0; j < 4; ++j) {
        float4 v = xr4[j * 64 + lane];
        float a0 = asin_clamped(v.x * scale, LO, HI);
        if ((j | lane) == 0) a0 = 0.0f;          // element 0 excluded
        sum += a0;
        sum += asin_clamped(v.y * scale, LO, HI);
        sum += asin_clamped(v.z * scale, LO, HI);
        sum += asin_clamped(v.w * scale, LO, HI);
    }
    #pragma unroll
    for (int off = 32; off > 0; off >>= 1)
        sum += __shfl_xor(sum, off, 64);

    float contrib = do_d ? ((float)lane * xd * tapd) : 0.0f;
    #pragma unroll
    for (int off = 8; off > 0; off >>= 1)
        contrib += __shfl_xor(contrib, off, 64);

    if (lane == 0) {
        phases_b[b * TT + t] = start + sum;
        const int s = (t < WIN) ? t : WIN;
        const float norm = 0.5f * (float)s * (float)(s + 1);
        tdiff_b[b * TT + t] = (norm > 0.0f) ? (contrib / norm) : 0.0f;
    }
}

// ---------------------------------------------------------------------------
// GEMM (M=16), 3-DEEP PIPELINE in R9 geometry: 512 blocks x 256 threads
// (2 blocks/CU), 8 cols/block (2/wave). KT=256, 4 LDS buffers (64 KB).
// Per tile per wave: 4 global_load_lds rows + 2 weight float4 = 6 vmem ops;
// steady-state s_waitcnt vmcnt(18) waits on a tile issued THREE phases
// (~1350 cyc) earlier -> HBM latency fully covered for stage AND weights.
// All buffer/register slots compile-time (4-phase unrolled groups).
// MODE 0: silu -> H_b[b*HALF + o].  MODE 1: tanh -> out[b*4096 + o*2 + g].
// ---------------------------------------------------------------------------
__device__ __forceinline__ void gld_lds16(const float* g, float* l) {
    __builtin_amdgcn_global_load_lds(
        (const __attribute__((address_space(1))) unsigned int*)g,
        (__attribute__((address_space(3))) unsigned int*)l,
        16, 0, 0);
}

template <int K, int MODE>
__global__ void __launch_bounds__(256)
gemm_kernel(const float* __restrict__ A0, const float* __restrict__ W0,
            const float* __restrict__ bias0, float* __restrict__ out0,
            const float* __restrict__ A1, const float* __restrict__ W1,
            const float* __restrict__ bias1, float* __restrict__ out1) {
    constexpr int KT = 256;
    constexpr int NT = K / KT;                    // 16 (G1) / 8 (G2): mult of 4
    __shared__ float als[4][16][KT];              // 64 KiB -> 2 blocks/CU

    const int nb = HALF / 8;                      // 256 blocks per problem
    const int g = blockIdx.x / nb;
    const int obase = (blockIdx.x % nb) * 8;

    const float* A    = g ? A1 : A0;
    const float* W    = g ? W1 : W0;
    const float* bias = g ? bias1 : bias0;
    float* out        = g ? out1 : out0;

    const int wv   = threadIdx.x >> 6;            // 0..3
    const int lane = threadIdx.x & 63;
    const int col0 = obase + wv * 2;
    const int col1 = col0 + 1;
    const float* w0p = W + (size_t)col0 * K + lane * 4;
    const float* w1p = W + (size_t)col1 * K + lane * 4;

    float4 wr0[4], wr1[4];                        // slot-indexed, static only
    float acc0[16], acc1[16];
    #pragma unroll
    for (int i = 0; i < 16; ++i) { acc0[i] = 0.0f; acc1[i] = 0.0f; }

// issue tile T into LDS slot T&3 + weight regs slot SL (compile-time SL):
// 4 gld_lds + 2 weight loads = 6 vmem ops, in order.
#define ISSUE(T, SL) do {                                                 \
        const int t_ = (T);                                               \
        const int s_ = t_ & 3;                                            \
        _Pragma("unroll")                                                 \
        for (int i = 0; i < 4; ++i) {                                     \
            const int br = wv * 4 + i;                                    \
            gld_lds16(A + (size_t)br * K + t_ * KT + lane * 4,            \
                      &als[s_][br][0]);                                   \
        }                                                                 \
        wr0[SL] = *(const float4*)(w0p + (size_t)t_ * KT);                \
        wr1[SL] = *(const float4*)(w1p + (size_t)t_ * KT);                \
    } while (0)

#define COMPUTE(S) do {                                                   \
        _Pragma("unroll")                                                 \
        for (int br = 0; br < 16; ++br) {                                 \
            const float4 a4 = *(const float4*)&als[S][br][lane * 4];      \
            acc0[br] += wr0[S].x*a4.x + wr0[S].y*a4.y                     \
                      + wr0[S].z*a4.z + wr0[S].w*a4.w;                    \
            acc1[br] += wr1[S].x*a4.x + wr1[S].y*a4.y                     \
                      + wr1[S].z*a4.z + wr1[S].w*a4.w;                    \
        }                                                                 \
    } while (0)

#define PHASE(S, DO_ISSUE, VMIMM) do {                                    \
        if (DO_ISSUE) ISSUE(tcur + (S) + 3, ((S) + 3) & 3);               \
        asm volatile("s_waitcnt vmcnt(" VMIMM ")" ::: "memory");          \
        __builtin_amdgcn_sched_barrier(0);                                \
        __builtin_amdgcn_s_barrier();                                     \
        COMPUTE((S));                                                     \
        __builtin_amdgcn_sched_barrier(0);                                \
        __builtin_amdgcn_s_barrier();                                     \
    } while (0)

    // prologue: tiles 0..2 in flight (18 vmem ops outstanding)
    ISSUE(0, 0);
    ISSUE(1, 1);
    ISSUE(2, 2);

    int tcur = 0;
    #pragma unroll 1
    for (; tcur + 7 < NT; tcur += 4) {            // all-issue groups
        PHASE(0, true, "18");
        PHASE(1, true, "18");
        PHASE(2, true, "18");
        PHASE(3, true, "18");
    }
    // final group (tcur == NT-4): one last issue, then drain 12/6/0
    PHASE(0, true,  "18");
    PHASE(1, false, "12");
    PHASE(2, false, "6");
    PHASE(3, false, "0");

#undef PHASE
#undef COMPUTE
#undef ISSUE

    // full-wave butterfly: every lane ends with complete sums
    #pragma unroll
    for (int off = 32; off > 0; off >>= 1) {
        #pragma unroll
        for (int i = 0; i < 16; ++i) {
            acc0[i] += __shfl_xor(acc0[i], off, 64);
            acc1[i] += __shfl_xor(acc1[i], off, 64);
        }
    }

    const bool isw0 = (lane == 0), isw1 = (lane == 32);
    if (isw0 || isw1) {
        const int o = isw0 ? col0 : col1;
        const float bs = bias[o];
        #pragma unroll
        for (int i = 0; i < 16; ++i) {
            float s = (isw0 ? acc0[i] : acc1[i]) + bs;
            if (MODE == 0) {
                s = s / (1.0f + expf(-s));        // silu
                out[(size_t)i * HALF + o] = s;    // H b-major [16][HALF]
            } else {
                s = tanhf(s);
                out[(size_t)i * (HALF * 2) + o * 2 + g] = s;
            }
        }
    }
}

extern "C" void kernel_launch(void* const* d_in, const int* in_sizes, int n_in,
                              void* d_out, int out_size, void* d_ws, size_t ws_size,
                              hipStream_t stream) {
    const float* x     = (const float*)d_in[0];
    const float* taper = (const float*)d_in[1];
    const float* cW1   = (const float*)d_in[2];
    const float* cb1   = (const float*)d_in[3];
    const float* cW2   = (const float*)d_in[4];
    const float* cb2   = (const float*)d_in[5];
    const float* pW1   = (const float*)d_in[6];
    const float* pb1   = (const float*)d_in[7];
    const float* pW2   = (const float*)d_in[8];
    const float* pb2   = (const float*)d_in[9];
    float* out = (float*)d_out;
    float* ws  = (float*)d_ws;

    float* phases_b = ws;                         // [16][4096]
    float* tdiff_b  = ws + 65536;                 // [16][4096]
    float* H1_b     = ws + 131072;                // [16][2048]
    float* H2_b     = ws + 163840;                // [16][2048]

    phase_tdiff_kernel<<<BB * TT / 4, 256, 0, stream>>>(x, taper, phases_b, tdiff_b);
    gemm_kernel<TT, 0><<<512, 256, 0, stream>>>(phases_b, cW1, cb1, H1_b,
                                                tdiff_b, pW1, pb1, H2_b);
    gemm_kernel<HALF, 1><<<512, 256, 0, stream>>>(H1_b, cW2, cb2, out,
                                                  H2_b, pW2, pb2, out);
}

// Round 20
// 97.722 us; speedup vs baseline: 1.1837x; 1.1837x over previous
//
#include <hip/hip_runtime.h>
#include <math.h>

#define BB 16
#define TT 4096
#define EE 1024
#define HALF 2048
#define WIN 15
#define EPSF 1e-6f
#define PI_F   3.14159265358979323846f
#define PIO2_F 1.57079632679489662f

// Minimal-issue branchless asin of clamp(t): ~18 VALU slots, raw HW sqrt.
__device__ __forceinline__ float asin_clamped(float t, float LO, float HI) {
    float c  = __builtin_amdgcn_fmed3f(t, LO, HI);   // clamp (1 op, no NaN here)
    float a  = fabsf(c);
    float z1 = c * c;
    float z2 = fmaf(a, -0.5f, 0.5f);                 // (1-a)/2
    bool big = a > 0.5f;
    float z  = big ? z2 : z1;
    float sq;
    asm("v_sqrt_f32 %0, %1" : "=v"(sq) : "v"(z2));   // raw, no IEEE fixup chain
    float s  = big ? sq : a;                         // s in [0, 0.5]
    float p = fmaf(z, 4.2163199048e-2f, 2.4181311049e-2f);
    p = fmaf(z, p, 4.5470025998e-2f);
    p = fmaf(z, p, 7.4953002686e-2f);
    p = fmaf(z, p, 1.6666752422e-1f);
    float r  = fmaf(s * z, p, s);                    // asin(s)
    float rb = fmaf(-2.0f, r, PIO2_F);               // pi/2 - 2*asin(s)
    r = big ? rb : r;
    return copysignf(r, c);
}

// ---------------------------------------------------------------------------
// Phase + fused tdiff (R15 frontier, verbatim): wave per row, b-major out.
// ---------------------------------------------------------------------------
__global__ void phase_tdiff_kernel(const float* __restrict__ x,
                                   const float* __restrict__ taper,
                                   float* __restrict__ phases_b,
                                   float* __restrict__ tdiff_b) {
    const int wave = threadIdx.x >> 6;
    const int lane = threadIdx.x & 63;
    const int row  = blockIdx.x * 4 + wave;      // [0, B*T)
    const int b = row >> 12;
    const int t = row & (TT - 1);
    const float tap = taper[t];
    const float* xr = x + (size_t)row * EE;

    float xd = 0.0f, tapd = 0.0f;
    const int td = t - lane;
    const bool do_d = (lane >= 1) && (lane <= WIN) && (lane <= t);
    if (do_d) {
        xd   = x[((size_t)b * TT + td) * EE];    // element 0 of row t-lane
        tapd = taper[td];
    }

    const float c0 = xr[0] * tap;
    const float r = fabsf(c0) + EPSF;
    const float scale = tap / r;
    const float start = (c0 >= 0.0f) ? 0.0f : PI_F;
    const float LO = -1.0f + EPSF, HI = 1.0f - EPSF;

    const float4* xr4 = (const float4*)xr;
    float sum = 0.0f;
    #pragma unroll
    for (int j = 0; j < 4; ++j) {
        float4 v = xr4[j * 64 + lane];
        float a0 = asin_clamped(v.x * scale, LO, HI);
        if ((j | lane) == 0) a0 = 0.0f;          // element 0 excluded
        sum += a0;
        sum += asin_clamped(v.y * scale, LO, HI);
        sum += asin_clamped(v.z * scale, LO, HI);
        sum += asin_clamped(v.w * scale, LO, HI);
    }
    #pragma unroll
    for (int off = 32; off > 0; off >>= 1)
        sum += __shfl_xor(sum, off, 64);

    float contrib = do_d ? ((float)lane * xd * tapd) : 0.0f;
    #pragma unroll
    for (int off = 8; off > 0; off >>= 1)
        contrib += __shfl_xor(contrib, off, 64);

    if (lane == 0) {
        phases_b[b * TT + t] = start + sum;
        const int s = (t < WIN) ? t : WIN;
        const float norm = 0.5f * (float)s * (float)(s + 1);
        tdiff_b[b * TT + t] = (norm > 0.0f) ? (contrib / norm) : 0.0f;
    }
}

// ---------------------------------------------------------------------------
// GEMM (R9 structure, VERBATIM — the 98.65 us frontier): KT=512 double-
// buffered LDS staging, counted vmcnt pipeline, 512 blocks x 256 threads,
// 8 cols/block (2/wave).
// MODE 0: silu -> H_b[b*HALF + o].  MODE 1: tanh -> out[b*4096 + o*2 + g].
// ---------------------------------------------------------------------------
__device__ __forceinline__ void gld_lds16(const float* g, float* l) {
    __builtin_amdgcn_global_load_lds(
        (const __attribute__((address_space(1))) unsigned int*)g,
        (__attribute__((address_space(3))) unsigned int*)l,
        16, 0, 0);
}

template <int K, int MODE>
__global__ void __launch_bounds__(256)
gemm_kernel(const float* __restrict__ A0, const float* __restrict__ W0,
            const float* __restrict__ bias0, float* __restrict__ out0,
            const float* __restrict__ A1, const float* __restrict__ W1,
            const float* __restrict__ bias1, float* __restrict__ out1) {
    constexpr int KT = 512;
    constexpr int NT = K / KT;
    constexpr int LROW = KT + 4;
    __shared__ float als[2][16 * LROW];

    const int nb = HALF / 8;                      // 256 blocks per problem
    const int g = blockIdx.x / nb;
    const int obase = (blockIdx.x % nb) * 8;

    const float* A    = g ? A1 : A0;
    const float* W    = g ? W1 : W0;
    const float* bias = g ? bias1 : bias0;
    float* out        = g ? out1 : out0;

    const int wv   = threadIdx.x >> 6;            // 0..3
    const int lane = threadIdx.x & 63;
    const int col0 = obase + wv * 2;
    const int col1 = col0 + 1;
    const float* w0p = W + (size_t)col0 * K;
    const float* w1p = W + (size_t)col1 * K;

    auto stage = [&](int t, int s) {
        #pragma unroll
        for (int i = 0; i < 4; ++i) {
            const int br = wv * 4 + i;
            const float* src = A + (size_t)br * K + t * KT + lane * 4;
            float* dst = &als[s][br * LROW];
            gld_lds16(src, dst);
            gld_lds16(src + 256, dst + 256);
        }
    };

    float acc0[16], acc1[16];
    #pragma unroll
    for (int i = 0; i < 16; ++i) { acc0[i] = 0.0f; acc1[i] = 0.0f; }

    stage(0, 0);

    for (int t = 0; t < NT; ++t) {
        const int cur = t & 1;

        float4 w0v[2], w1v[2];
        #pragma unroll
        for (int s2 = 0; s2 < 2; ++s2) {
            w0v[s2] = *(const float4*)(w0p + t * KT + s2 * 256 + lane * 4);
            w1v[s2] = *(const float4*)(w1p + t * KT + s2 * 256 + lane * 4);
        }

        if (t + 1 < NT) {
            stage(t + 1, cur ^ 1);
            asm volatile("s_waitcnt vmcnt(8)" ::: "memory");
        } else {
            asm volatile("s_waitcnt vmcnt(0)" ::: "memory");
        }
        __builtin_amdgcn_s_barrier();
        __builtin_amdgcn_sched_barrier(0);

        #pragma unroll
        for (int s2 = 0; s2 < 2; ++s2) {
            #pragma unroll
            for (int br = 0; br < 16; ++br) {
                const float4 a4 = *(const float4*)&als[cur][br * LROW + s2 * 256 + lane * 4];
                acc0[br] += w0v[s2].x*a4.x + w0v[s2].y*a4.y + w0v[s2].z*a4.z + w0v[s2].w*a4.w;
                acc1[br] += w1v[s2].x*a4.x + w1v[s2].y*a4.y + w1v[s2].z*a4.z + w1v[s2].w*a4.w;
            }
        }
        __builtin_amdgcn_sched_barrier(0);
        __builtin_amdgcn_s_barrier();
    }

    #pragma unroll
    for (int off = 32; off > 0; off >>= 1) {
        #pragma unroll
        for (int i = 0; i < 16; ++i) {
            acc0[i] += __shfl_xor(acc0[i], off, 64);
            acc1[i] += __shfl_xor(acc1[i], off, 64);
        }
    }

    const bool isw0 = (lane == 0), isw1 = (lane == 32);
    if (isw0 || isw1) {
        const int o = isw0 ? col0 : col1;
        const float bs = bias[o];
        #pragma unroll
        for (int i = 0; i < 16; ++i) {
            float s = (isw0 ? acc0[i] : acc1[i]) + bs;
            if (MODE == 0) {
                s = s / (1.0f + expf(-s));
                out[(size_t)i * HALF + o] = s;
            } else {
                s = tanhf(s);
                out[(size_t)i * (HALF * 2) + o * 2 + g] = s;
            }
        }
    }
}

extern "C" void kernel_launch(void* const* d_in, const int* in_sizes, int n_in,
                              void* d_out, int out_size, void* d_ws, size_t ws_size,
                              hipStream_t stream) {
    const float* x     = (const float*)d_in[0];
    const float* taper = (const float*)d_in[1];
    const float* cW1   = (const float*)d_in[2];
    const float* cb1   = (const float*)d_in[3];
    const float* cW2   = (const float*)d_in[4];
    const float* cb2   = (const float*)d_in[5];
    const float* pW1   = (const float*)d_in[6];
    const float* pb1   = (const float*)d_in[7];
    const float* pW2   = (const float*)d_in[8];
    const float* pb2   = (const float*)d_in[9];
    float* out = (float*)d_out;
    float* ws  = (float*)d_ws;

    float* phases_b = ws;                         // [16][4096]
    float* tdiff_b  = ws + 65536;                 // [16][4096]
    float* H1_b     = ws + 131072;                // [16][2048]
    float* H2_b     = ws + 163840;                // [16][2048]

    phase_tdiff_kernel<<<BB * TT / 4, 256, 0, stream>>>(x, taper, phases_b, tdiff_b);
    gemm_kernel<TT, 0><<<512, 256, 0, stream>>>(phases_b, cW1, cb1, H1_b,
                                                tdiff_b, pW1, pb1, H2_b);
    gemm_kernel<HALF, 1><<<512, 256, 0, stream>>>(H1_b, cW2, cb2, out,
                                                  H2_b, pW2, pb2, out);
}